// Round 12
// baseline (106.443 us; speedup 1.0000x reference)
//
#include <hip/hip_runtime.h>
#include <stdint.h>

#define BB 4
#define NN 32768
#define PRE 4096
#define POST 512
#define NMS_TH 0.7f
#define MIDCAP 8192
#define P1G 16            // phase-1 groups (rows 0..1023)

typedef unsigned long long u64;
typedef unsigned int u32;

__device__ __forceinline__ u32 orderable(float f) {
  u32 u = __float_as_uint(f);
  return (u & 0x80000000u) ? ~u : (u | 0x80000000u);
}
__device__ __forceinline__ float unorderable(u32 o) {
  u32 u = (o & 0x80000000u) ? (o & 0x7fffffffu) : ~o;
  return __uint_as_float(u);
}
// Monotone fixed-point bucket: uniform in score space (scores in [0,1)).
__device__ __forceinline__ u32 bucket_of(float s) {
  u32 v = (u32)(s * 2147483648.0f);
  u32 bk = v >> 20;
  return bk > 2047u ? 2047u : bk;
}
// Wave-uniform 64-bit readlane (2x v_readlane -> SGPRs; result is uniform so
// downstream 64-bit arithmetic compiles to SALU s_*_b64 ops).
__device__ __forceinline__ u64 readlane64(u64 v, int l) {
  u32 lo = (u32)__builtin_amdgcn_readlane((int)(u32)v, l);
  u32 hi = (u32)__builtin_amdgcn_readlane((int)(u32)(v >> 32), l);
  return ((u64)hi << 32) | lo;
}

// Zero the histogram + mid counter (ws is not re-poisoned between replays).
__global__ void zero_kernel(u32* __restrict__ hist, u32* __restrict__ cnt_mid) {
  int t = blockIdx.x * 256 + threadIdx.x;
  if (t < BB * 2048) hist[t] = 0;
  if (t < BB) cnt_mid[t] = 0;
}

// score = max over 3 classes, label = first argmax, key = orderable(score)||~idx.
// Histogram fixed-point bucket per batch.
__global__ __launch_bounds__(256) void score_hist_kernel(const float* __restrict__ cls,
                                                         int* __restrict__ labels,
                                                         u64* __restrict__ keys,
                                                         u32* __restrict__ hist) {
  __shared__ u32 lh[2048];
  for (int t = threadIdx.x; t < 2048; t += 256) lh[t] = 0;
  __syncthreads();
  int g = blockIdx.x * 256 + threadIdx.x;           // BB*NN is an exact multiple of 256
  const float* c = cls + (size_t)g * 3;
  float s = c[0]; int l = 0;
  float c1 = c[1], c2 = c[2];
  if (c1 > s) { s = c1; l = 1; }
  if (c2 > s) { s = c2; l = 2; }
  int n = g & (NN - 1);
  keys[g] = ((u64)orderable(s) << 32) | (u32)(~(u32)n);
  labels[g] = l;
  atomicAdd(&lh[bucket_of(s)], 1u);
  __syncthreads();
  int b = blockIdx.x >> 7;                           // 128 blocks per batch
  for (int t = threadIdx.x; t < 2048; t += 256) {
    u32 v = lh[t];
    if (v) atomicAdd(&hist[b * 2048 + t], v);
  }
}

// Per batch: suffix-scan the histogram; find threshold bucket T with
// count(>T) < PRE <= count(>=T); persist sfx and init per-bucket cursors
// (cursor[t] = start of bucket t's segment in the final descending order).
__global__ __launch_bounds__(256) void select_kernel(const u32* __restrict__ hist,
                                                     u32* __restrict__ selinfo,
                                                     u32* __restrict__ sfxBuf,
                                                     u32* __restrict__ cursor) {
  __shared__ u32 sfx[2048];
  int b = blockIdx.x;
  for (int t = threadIdx.x; t < 2048; t += 256) sfx[t] = hist[b * 2048 + t];
  __syncthreads();
  for (int d = 1; d < 2048; d <<= 1) {
    u32 v[8];
#pragma unroll
    for (int i = 0; i < 8; ++i) {
      int t = threadIdx.x + i * 256;
      v[i] = (t + d < 2048) ? sfx[t + d] : 0;
    }
    __syncthreads();
#pragma unroll
    for (int i = 0; i < 8; ++i) sfx[threadIdx.x + i * 256] += v[i];
    __syncthreads();
  }
  for (int t = threadIdx.x; t < 2048; t += 256) {
    u32 above = (t + 1 < 2048) ? sfx[t + 1] : 0;
    sfxBuf[b * 2048 + t] = sfx[t];
    cursor[b * 2048 + t] = above;                       // segment base
    if (above < PRE && sfx[t] >= PRE) { selinfo[b * 2] = (u32)t; selinfo[b * 2 + 1] = above; }
  }
}

// Compact: hi keys scatter directly into their bucket's segment of sel via
// per-bucket cursors (2048 addresses/batch -> low contention); mid keys go to
// the tie-break buffer. Within-segment order arbitrary; bsort fixes it.
__global__ __launch_bounds__(256) void compact_kernel(const u64* __restrict__ keys,
                                                      const u32* __restrict__ selinfo,
                                                      u32* __restrict__ cursor,
                                                      u64* __restrict__ sel, u64* __restrict__ mid,
                                                      u32* __restrict__ cnt_mid) {
  int g = blockIdx.x * 256 + threadIdx.x;
  int b = g >> 15;
  u64 key = keys[g];
  u32 bk = bucket_of(unorderable((u32)(key >> 32)));
  u32 T = selinfo[b * 2];
  if (bk > T) {
    u32 p = atomicAdd(&cursor[b * 2048 + bk], 1u);
    sel[((size_t)b << 12) + p] = key;
  } else if (bk == T) {
    u32 p = atomicAdd(&cnt_mid[b], 1u);
    if (p < MIDCAP) mid[(size_t)b * MIDCAP + p] = key;   // ~45 expected with this data
  }
}

// One wave per (batch, bucket). Buckets > T: in-register 64-lane bitonic sort
// of the segment. Bucket == T: top (PRE-C1) mid keys by wave argmax (fused
// midsel). Then: FUSED GATHER — each wave gathers box data for its final
// segment of sel (deletes the separate gather_kernel launch).
__global__ __launch_bounds__(64) void bsort_kernel(u64* __restrict__ sel, u64* __restrict__ mid,
                                                   const u32* __restrict__ sfxBuf,
                                                   const u32* __restrict__ selinfo,
                                                   const u32* __restrict__ cnt_mid,
                                                   const float* __restrict__ boxes,
                                                   const int* __restrict__ labels,
                                                   float* __restrict__ topBox,
                                                   float4* __restrict__ P,
                                                   float* __restrict__ AR,
                                                   float* __restrict__ topS,
                                                   int* __restrict__ topL) {
  int t = blockIdx.x & 2047;
  int b = blockIdx.x >> 11;
  int lane = threadIdx.x;
  u32 T = selinfo[b * 2];
  if ((u32)t < T) return;
  u64* selB = sel + ((size_t)b << 12);
  u32 start, end;
  if ((u32)t == T) {
    u32 C1 = selinfo[b * 2 + 1];
    int need = PRE - (int)C1;
    int M = (int)cnt_mid[b]; if (M > MIDCAP) M = MIDCAP;
    u64* midB = mid + (size_t)b * MIDCAP;
    for (int r = 0; r < need; ++r) {
      u64 best = 0; int bi = -1;
      for (int q = lane; q < M; q += 64) {
        u64 v = midB[q];
        if (v > best) { best = v; bi = q; }
      }
#pragma unroll
      for (int d = 32; d > 0; d >>= 1) {
        u64 ob = __shfl_xor(best, d, 64);
        int oi = __shfl_xor(bi, d, 64);
        if (ob > best) { best = ob; bi = oi; }
      }
      if (lane == 0) selB[C1 + r] = best;
      if (bi >= 0 && lane == (bi & 63)) midB[bi] = 0;    // remove chosen
    }
    start = C1; end = PRE;
  } else {
    start = (t < 2047) ? sfxBuf[b * 2048 + t + 1] : 0u;
    end = sfxBuf[b * 2048 + t];
    int n = (int)(end - start);
    if (n > 64) {
      // robustness fallback (never hit on bench data): selection sort by wave argmax
      for (int r = 0; r < n - 1; ++r) {
        u64 best = 0; int bi = -1;
        for (int q = r + lane; q < n; q += 64) {
          u64 v = selB[start + q];
          if (v > best) { best = v; bi = q; }
        }
#pragma unroll
        for (int d = 32; d > 0; d >>= 1) {
          u64 ob = __shfl_xor(best, d, 64);
          int oi = __shfl_xor(bi, d, 64);
          if (ob > best) { best = ob; bi = oi; }
        }
        if (lane == 0) {
          u64 tmp = selB[start + r];
          selB[start + r] = best;
          selB[start + bi] = tmp;
        }
      }
    } else if (n > 1) {
      u64 v = (lane < n) ? selB[start + lane] : 0ULL;    // real keys have MSB set -> pad sinks
#pragma unroll
      for (int k = 2; k <= 64; k <<= 1) {
#pragma unroll
        for (int j = k >> 1; j > 0; j >>= 1) {
          u64 o = __shfl_xor(v, j, 64);
          bool up = ((lane & k) == 0);                   // k=64 -> desc everywhere
          bool first = ((lane & j) == 0);
          u64 mx = v > o ? v : o, mn = v > o ? o : v;
          v = (first == up) ? mx : mn;
        }
      }
      if (lane < n) selB[start + lane] = v;
    }
  }
  __builtin_amdgcn_s_waitcnt(0);                         // selB writes visible to this wave
  // ---- fused gather for this wave's final segment [start, end) ----
  for (u32 pos = start + lane; pos < end; pos += 64) {
    u64 key = selB[pos];
    u32 n = ~(u32)key;
    size_t src = (size_t)b * NN + n;
    const float* bx = boxes + src * 7;
    float x = bx[0], y = bx[1], dx = bx[3], dy = bx[4];
    size_t gidx = ((size_t)b << 12) + pos;
    float* tb = topBox + gidx * 7;
#pragma unroll
    for (int c = 0; c < 7; ++c) tb[c] = bx[c];
    float4 p;
    p.x = x - 0.5f * dx; p.z = x + 0.5f * dx;   // 0.5*dx exact -> contraction-safe
    p.y = y - 0.5f * dy; p.w = y + 0.5f * dy;
    P[gidx] = p;
    AR[gidx] = dx * dy;
    topS[gidx] = unorderable((u32)(key >> 32));
    topL[gidx] = labels[src];
  }
}

// One 64x64 tile (rb, w) of the suppression mask. Lane = row; column boxes
// loaded from wave-uniform addresses (scalarizable). Fast path: inter > 0.7*denom
// with min-margin tracking; if ANY lane of the tile is within the conservative
// band (rel 2e-5 >> max rounding skew ~4e-7), redo the whole word with the exact
// IEEE divide (wave-uniform rare path) -> decisions bitwise == numpy.
__device__ __forceinline__ void mask_tile(int b, int rb, int w, int lane,
                                          const float4* __restrict__ P,
                                          const float* __restrict__ AR,
                                          u64* __restrict__ maskT,
                                          u64* __restrict__ diag) {
  int base = b << 12;
  int row = (rb << 6) + lane;
  float4 rp = P[base + row];
  float rar = AR[base + row];
  const float4* __restrict__ Pcol = P + base + (w << 6);   // wave-uniform base
  const float* __restrict__ ARcol = AR + base + (w << 6);
  u64 bits = 0;
  float margMin = 1.0f;
#pragma unroll 8
  for (int k = 0; k < 64; ++k) {
    float4 cb = Pcol[k];
    float ca = ARcol[k];
    float ix = fminf(rp.z, cb.z) - fmaxf(rp.x, cb.x); ix = fmaxf(0.0f, ix);
    float iy = fminf(rp.w, cb.w) - fmaxf(rp.y, cb.y); iy = fmaxf(0.0f, iy);
    float inter = ix * iy;
    float denom = ((rar + ca) - inter) + 1e-6f;      // same op order as reference
    float t = 0.7f * denom;                          // denom >= 1 here, t > 0
    bits |= ((u64)(inter > t ? 1u : 0u)) << k;
    margMin = fminf(margMin, fabsf(inter - t) - 2e-5f * t);
  }
  if (__any(margMin <= 0.0f)) {                      // rare: near-threshold lane
    bits = 0;
    for (int k = 0; k < 64; ++k) {
      float4 cb = Pcol[k];
      float ca = ARcol[k];
      float ix = fminf(rp.z, cb.z) - fmaxf(rp.x, cb.x); ix = fmaxf(0.0f, ix);
      float iy = fminf(rp.w, cb.w) - fmaxf(rp.y, cb.y); iy = fmaxf(0.0f, iy);
      float inter = ix * iy;
      float denom = ((rar + ca) - inter) + 1e-6f;
      bits |= ((u64)(((inter / denom) > NMS_TH) ? 1u : 0u)) << k;
    }
  }
  maskT[((size_t)(b * 64 + w)) * PRE + row] = bits;  // word-major: coalesced 512B
  if (w == rb) diag[base + row] = bits;
}

// Phase 1: tiles with rb < P1G (rows 0..1023), w >= rb. 904 tiles/batch.
__global__ __launch_bounds__(256) void mask1_kernel(const float4* __restrict__ P,
                                                    const float* __restrict__ AR,
                                                    u64* __restrict__ maskT,
                                                    u64* __restrict__ diag) {
  int b = blockIdx.y;
  int ti = blockIdx.x * 4 + (threadIdx.x >> 6);       // [0, 904)
  int lane = threadIdx.x & 63;
  int rb = 0;                                         // row start(rb) = 64rb - rb(rb-1)/2
  while (rb < P1G - 1 && (64 * (rb + 1) - ((rb + 1) * rb) / 2) <= ti) ++rb;
  int w = rb + (ti - (64 * rb - (rb * (rb - 1)) / 2));
  mask_tile(b, rb, w, lane, P, AR, maskT, diag);
}

// Phase 2: tiles with rb >= P1G; no-op when scan phase 0 already found 512 keeps.
__global__ __launch_bounds__(256) void mask2_kernel(const float4* __restrict__ P,
                                                    const float* __restrict__ AR,
                                                    u64* __restrict__ maskT,
                                                    u64* __restrict__ diag,
                                                    const u32* __restrict__ doneFlag) {
  int b = blockIdx.y;
  if (doneFlag[b]) return;
  int ti = blockIdx.x * 4 + (threadIdx.x >> 6);       // [0, 1176)
  int lane = threadIdx.x & 63;
  int rr = 0;                                         // row start(rr) = 48rr - rr(rr-1)/2
  while (rr < 47 && (48 * (rr + 1) - ((rr + 1) * rr) / 2) <= ti) ++rr;
  int rb = rr + P1G;
  int w = rb + (ti - (48 * rr - (rr * (rr - 1)) / 2));
  mask_tile(b, rb, w, lane, P, AR, maskT, diag);
}

// Greedy scan, group-of-64, two-phase with state carry. One wave per batch.
// Per group: (a) ballot fast-path — if no diag word in the group has any bit
// (the ~98% case with sparse suppression), keep = ~sup with ZERO recurrence
// steps; else the SALU readlane recurrence. (b) remv row loads are STREAMED
// into the gated OR (no 128-VGPR rv array -> no scratch spill; this was the
// R10/R11 40us bottleneck). __launch_bounds__(64,1) uncaps the allocator.
__global__ __launch_bounds__(64, 1) void scan_kernel(const u64* __restrict__ maskT,
                                                     const u64* __restrict__ diag,
                                                     const float* __restrict__ topBox,
                                                     const float* __restrict__ topS,
                                                     const int* __restrict__ topL,
                                                     float* __restrict__ out,
                                                     u64* __restrict__ rState,
                                                     u64* __restrict__ kwState,
                                                     u32* __restrict__ nkState,
                                                     u32* __restrict__ doneFlag,
                                                     int phase) {
  __shared__ u64 kwLDS[64];
  int b = blockIdx.x;
  int lane = threadIdx.x;
  if (phase == 1 && doneFlag[b]) return;
  const u64* m = maskT + (size_t)b * 64 * PRE;
  const u64* dg = diag + (size_t)b * PRE;
  u64 r; int nk, gs, ge;
  if (phase == 0) {
    kwLDS[lane] = 0; r = 0; nk = 0; gs = 0; ge = P1G;
  } else {
    kwLDS[lane] = (lane < P1G) ? kwState[b * 64 + lane] : 0;
    r = rState[b * 64 + lane]; nk = nkState[b]; gs = P1G; ge = 64;
  }
  __syncthreads();
  bool done = false;
  u64 d_next = dg[(size_t)gs * 64 + lane];           // diag prefetch, 1 group ahead
  for (int g = gs; g < ge; ++g) {
    u64 d_cur = d_next;
    if (g + 1 < ge) d_next = dg[(size_t)(g + 1) * 64 + lane];
    // ---- decision: fast path (no intra-group suppression bits) or recurrence ----
    u64 sup = readlane64(r, g);
    u64 keep;
    u64 anyd = __ballot(d_cur != 0ULL);              // rows with any diag bits
    if (anyd == 0ULL) {
      keep = ~sup;                                   // no recurrence needed
    } else {
      keep = 0;
#pragma unroll
      for (int k = 0; k < 64; ++k) {
        u64 dk = readlane64(d_cur, k);               // compile-time lane index
        u64 bit = (sup >> k) & 1ULL;
        keep |= (bit ^ 1ULL) << k;
        sup |= (dk & ~((2ULL << k) - 1ULL)) & (bit - 1ULL);
      }
    }
    // ---- per-lane remv update: STREAMED loads, gated by uniform keep ----
    const ulonglong2* mp = (const ulonglong2*)(m + (size_t)lane * PRE + ((size_t)g << 6));
    u64 acc = 0;
#pragma unroll
    for (int q = 0; q < 32; ++q) {
      ulonglong2 v = mp[q];                          // consumed immediately -> no spill
      u64 g0 = 0ULL - ((keep >> (2 * q)) & 1ULL);
      u64 g1 = 0ULL - ((keep >> (2 * q + 1)) & 1ULL);
      acc |= (v.x & g0) | (v.y & g1);
    }
    r |= acc;
    if (lane == 0) kwLDS[g] = keep;
    nk += (int)__popcll(keep);                       // uniform -> s_bcnt1
    if (nk >= POST) { done = true; break; }
  }
  __syncthreads();
  if (phase == 0 && !done) {                       // save state for phase 1
    rState[b * 64 + lane] = r;
    if (lane < P1G) kwState[b * 64 + lane] = kwLDS[lane];
    if (lane == 0) { nkState[b] = nk; doneFlag[b] = 0; }
    return;
  }
  if (phase == 0 && lane == 0) doneFlag[b] = 1;
  // ---- finalize: expand keep words, write output directly ----
  u64 kw = kwLDS[lane];
  int cnt = __popcll(kw);
  int pfx = cnt;
#pragma unroll
  for (int d = 1; d < 64; d <<= 1) {
    int up = __shfl_up(pfx, d, 64);
    if (lane >= d) pfx += up;
  }
  int total = __shfl(pfx, 63, 64);
  int pos = pfx - cnt;
  float* outR = out;
  float* outS = out + BB * POST * 7;
  float* outL = outS + BB * POST;
  while (kw) {
    int t = __ffsll((long long)kw) - 1;
    kw &= kw - 1;
    if (pos < POST) {
      int i = (lane << 6) + t;
      int g = (b << 9) + pos;
      const float* tb = topBox + ((size_t)(b << 12) + i) * 7;
#pragma unroll
      for (int c = 0; c < 7; ++c) outR[(size_t)g * 7 + c] = tb[c];
      outS[g] = topS[(b << 12) + i];
      outL[g] = (float)(topL[(b << 12) + i] + 1);
    }
    ++pos;
  }
  int fin = total < POST ? total : POST;
  for (int s = fin + lane; s < POST; s += 64) {     // empty slots: 0 / 0 / label 1
    int g = (b << 9) + s;
#pragma unroll
    for (int c = 0; c < 7; ++c) outR[(size_t)g * 7 + c] = 0.0f;
    outS[g] = 0.0f;
    outL[g] = 1.0f;
  }
}

extern "C" void kernel_launch(void* const* d_in, const int* in_sizes, int n_in,
                              void* d_out, int out_size, void* d_ws, size_t ws_size,
                              hipStream_t stream) {
  const float* boxes = (const float*)d_in[0];   // (4,32768,7)
  const float* cls   = (const float*)d_in[1];   // (4,32768,3)
  float* out = (float*)d_out;

  // ---- workspace carve-up (~11 MB) ----
  char* p = (char*)d_ws;
  auto take = [&](size_t bytes) { char* r = p; p += (bytes + 255) & ~(size_t)255; return (void*)r; };
  u64*   keys    = (u64*)  take((size_t)BB * NN * 8);
  int*   labels  = (int*)  take((size_t)BB * NN * 4);
  u32*   hist    = (u32*)  take((size_t)BB * 2048 * 4);
  u32*   selinfo = (u32*)  take((size_t)BB * 2 * 4);
  u32*   sfxBuf  = (u32*)  take((size_t)BB * 2048 * 4);
  u32*   cursor  = (u32*)  take((size_t)BB * 2048 * 4);
  u32*   cnt_mid = (u32*)  take((size_t)BB * 4);
  u64*   sel     = (u64*)  take((size_t)BB * PRE * 8);
  u64*   mid     = (u64*)  take((size_t)BB * MIDCAP * 8);
  float* topBox  = (float*)take((size_t)BB * PRE * 7 * 4);
  float4* Pb     = (float4*)take((size_t)BB * PRE * 16);
  float* AR      = (float*)take((size_t)BB * PRE * 4);
  float* topS    = (float*)take((size_t)BB * PRE * 4);
  int*   topL    = (int*)  take((size_t)BB * PRE * 4);
  u64*   maskT   = (u64*)  take((size_t)BB * 64 * PRE * 8);
  u64*   diagBuf = (u64*)  take((size_t)BB * PRE * 8);
  u64*   rState  = (u64*)  take((size_t)BB * 64 * 8);
  u64*   kwState = (u64*)  take((size_t)BB * 64 * 8);
  u32*   nkState = (u32*)  take((size_t)BB * 4);
  u32*   doneFlg = (u32*)  take((size_t)BB * 4);

  zero_kernel<<<32, 256, 0, stream>>>(hist, cnt_mid);
  score_hist_kernel<<<BB * NN / 256, 256, 0, stream>>>(cls, labels, keys, hist);
  select_kernel<<<BB, 256, 0, stream>>>(hist, selinfo, sfxBuf, cursor);
  compact_kernel<<<BB * NN / 256, 256, 0, stream>>>(keys, selinfo, cursor, sel, mid, cnt_mid);
  bsort_kernel<<<BB * 2048, 64, 0, stream>>>(sel, mid, sfxBuf, selinfo, cnt_mid,
                                             boxes, labels, topBox, Pb, AR, topS, topL);
  mask1_kernel<<<dim3(226, BB), 256, 0, stream>>>(Pb, AR, maskT, diagBuf);
  scan_kernel<<<BB, 64, 0, stream>>>(maskT, diagBuf, topBox, topS, topL, out,
                                     rState, kwState, nkState, doneFlg, 0);
  mask2_kernel<<<dim3(294, BB), 256, 0, stream>>>(Pb, AR, maskT, diagBuf, doneFlg);
  scan_kernel<<<BB, 64, 0, stream>>>(maskT, diagBuf, topBox, topS, topL, out,
                                     rState, kwState, nkState, doneFlg, 1);
}

// Round 13
// 101.903 us; speedup vs baseline: 1.0446x; 1.0446x over previous
//
#include <hip/hip_runtime.h>
#include <stdint.h>

#define BB 4
#define NN 32768
#define PRE 4096
#define POST 512
#define NMS_TH 0.7f
#define MIDCAP 8192
#define P1G 16            // phase-1 groups (rows 0..1023)

typedef unsigned long long u64;
typedef unsigned int u32;

__device__ __forceinline__ u32 orderable(float f) {
  u32 u = __float_as_uint(f);
  return (u & 0x80000000u) ? ~u : (u | 0x80000000u);
}
__device__ __forceinline__ float unorderable(u32 o) {
  u32 u = (o & 0x80000000u) ? (o & 0x7fffffffu) : ~o;
  return __uint_as_float(u);
}
// Monotone fixed-point bucket: uniform in score space (scores in [0,1)).
__device__ __forceinline__ u32 bucket_of(float s) {
  u32 v = (u32)(s * 2147483648.0f);
  u32 bk = v >> 20;
  return bk > 2047u ? 2047u : bk;
}
// Wave-uniform 64-bit readlane (2x v_readlane -> SGPRs; result is uniform so
// downstream 64-bit arithmetic compiles to SALU s_*_b64 ops).
__device__ __forceinline__ u64 readlane64(u64 v, int l) {
  u32 lo = (u32)__builtin_amdgcn_readlane((int)(u32)v, l);
  u32 hi = (u32)__builtin_amdgcn_readlane((int)(u32)(v >> 32), l);
  return ((u64)hi << 32) | lo;
}

// Zero histogram + mid counter + row-any bitmap (ws not re-poisoned between replays).
__global__ void zero_kernel(u32* __restrict__ hist, u32* __restrict__ cnt_mid,
                            u64* __restrict__ rowAnyBm) {
  int t = blockIdx.x * 256 + threadIdx.x;
  if (t < BB * 2048) hist[t] = 0;
  if (t < BB * 64) rowAnyBm[t] = 0;
  if (t < BB) cnt_mid[t] = 0;
}

// score = max over 3 classes, label = first argmax, key = orderable(score)||~idx.
// Histogram fixed-point bucket per batch.
__global__ __launch_bounds__(256) void score_hist_kernel(const float* __restrict__ cls,
                                                         int* __restrict__ labels,
                                                         u64* __restrict__ keys,
                                                         u32* __restrict__ hist) {
  __shared__ u32 lh[2048];
  for (int t = threadIdx.x; t < 2048; t += 256) lh[t] = 0;
  __syncthreads();
  int g = blockIdx.x * 256 + threadIdx.x;           // BB*NN is an exact multiple of 256
  const float* c = cls + (size_t)g * 3;
  float s = c[0]; int l = 0;
  float c1 = c[1], c2 = c[2];
  if (c1 > s) { s = c1; l = 1; }
  if (c2 > s) { s = c2; l = 2; }
  int n = g & (NN - 1);
  keys[g] = ((u64)orderable(s) << 32) | (u32)(~(u32)n);
  labels[g] = l;
  atomicAdd(&lh[bucket_of(s)], 1u);
  __syncthreads();
  int b = blockIdx.x >> 7;                           // 128 blocks per batch
  for (int t = threadIdx.x; t < 2048; t += 256) {
    u32 v = lh[t];
    if (v) atomicAdd(&hist[b * 2048 + t], v);
  }
}

// Per batch: suffix-scan the histogram; find threshold bucket T with
// count(>T) < PRE <= count(>=T); persist sfx and init per-bucket cursors
// (cursor[t] = start of bucket t's segment in the final descending order).
__global__ __launch_bounds__(256) void select_kernel(const u32* __restrict__ hist,
                                                     u32* __restrict__ selinfo,
                                                     u32* __restrict__ sfxBuf,
                                                     u32* __restrict__ cursor) {
  __shared__ u32 sfx[2048];
  int b = blockIdx.x;
  for (int t = threadIdx.x; t < 2048; t += 256) sfx[t] = hist[b * 2048 + t];
  __syncthreads();
  for (int d = 1; d < 2048; d <<= 1) {
    u32 v[8];
#pragma unroll
    for (int i = 0; i < 8; ++i) {
      int t = threadIdx.x + i * 256;
      v[i] = (t + d < 2048) ? sfx[t + d] : 0;
    }
    __syncthreads();
#pragma unroll
    for (int i = 0; i < 8; ++i) sfx[threadIdx.x + i * 256] += v[i];
    __syncthreads();
  }
  for (int t = threadIdx.x; t < 2048; t += 256) {
    u32 above = (t + 1 < 2048) ? sfx[t + 1] : 0;
    sfxBuf[b * 2048 + t] = sfx[t];
    cursor[b * 2048 + t] = above;                       // segment base
    if (above < PRE && sfx[t] >= PRE) { selinfo[b * 2] = (u32)t; selinfo[b * 2 + 1] = above; }
  }
}

// Compact: hi keys scatter directly into their bucket's segment of sel via
// per-bucket cursors (2048 addresses/batch -> low contention); mid keys go to
// the tie-break buffer. Within-segment order arbitrary; bsort fixes it.
__global__ __launch_bounds__(256) void compact_kernel(const u64* __restrict__ keys,
                                                      const u32* __restrict__ selinfo,
                                                      u32* __restrict__ cursor,
                                                      u64* __restrict__ sel, u64* __restrict__ mid,
                                                      u32* __restrict__ cnt_mid) {
  int g = blockIdx.x * 256 + threadIdx.x;
  int b = g >> 15;
  u64 key = keys[g];
  u32 bk = bucket_of(unorderable((u32)(key >> 32)));
  u32 T = selinfo[b * 2];
  if (bk > T) {
    u32 p = atomicAdd(&cursor[b * 2048 + bk], 1u);
    sel[((size_t)b << 12) + p] = key;
  } else if (bk == T) {
    u32 p = atomicAdd(&cnt_mid[b], 1u);
    if (p < MIDCAP) mid[(size_t)b * MIDCAP + p] = key;   // ~45 expected with this data
  }
}

// One wave per (batch, bucket). Buckets > T: in-register 64-lane bitonic sort
// of the segment. Bucket == T: top (PRE-C1) mid keys by wave argmax (fused
// midsel). Then: FUSED GATHER — each wave gathers box data for its final
// segment of sel.
__global__ __launch_bounds__(64) void bsort_kernel(u64* __restrict__ sel, u64* __restrict__ mid,
                                                   const u32* __restrict__ sfxBuf,
                                                   const u32* __restrict__ selinfo,
                                                   const u32* __restrict__ cnt_mid,
                                                   const float* __restrict__ boxes,
                                                   const int* __restrict__ labels,
                                                   float* __restrict__ topBox,
                                                   float4* __restrict__ P,
                                                   float* __restrict__ AR,
                                                   float* __restrict__ topS,
                                                   int* __restrict__ topL) {
  int t = blockIdx.x & 2047;
  int b = blockIdx.x >> 11;
  int lane = threadIdx.x;
  u32 T = selinfo[b * 2];
  if ((u32)t < T) return;
  u64* selB = sel + ((size_t)b << 12);
  u32 start, end;
  if ((u32)t == T) {
    u32 C1 = selinfo[b * 2 + 1];
    int need = PRE - (int)C1;
    int M = (int)cnt_mid[b]; if (M > MIDCAP) M = MIDCAP;
    u64* midB = mid + (size_t)b * MIDCAP;
    for (int r = 0; r < need; ++r) {
      u64 best = 0; int bi = -1;
      for (int q = lane; q < M; q += 64) {
        u64 v = midB[q];
        if (v > best) { best = v; bi = q; }
      }
#pragma unroll
      for (int d = 32; d > 0; d >>= 1) {
        u64 ob = __shfl_xor(best, d, 64);
        int oi = __shfl_xor(bi, d, 64);
        if (ob > best) { best = ob; bi = oi; }
      }
      if (lane == 0) selB[C1 + r] = best;
      if (bi >= 0 && lane == (bi & 63)) midB[bi] = 0;    // remove chosen
    }
    start = C1; end = PRE;
  } else {
    start = (t < 2047) ? sfxBuf[b * 2048 + t + 1] : 0u;
    end = sfxBuf[b * 2048 + t];
    int n = (int)(end - start);
    if (n > 64) {
      // robustness fallback (never hit on bench data): selection sort by wave argmax
      for (int r = 0; r < n - 1; ++r) {
        u64 best = 0; int bi = -1;
        for (int q = r + lane; q < n; q += 64) {
          u64 v = selB[start + q];
          if (v > best) { best = v; bi = q; }
        }
#pragma unroll
        for (int d = 32; d > 0; d >>= 1) {
          u64 ob = __shfl_xor(best, d, 64);
          int oi = __shfl_xor(bi, d, 64);
          if (ob > best) { best = ob; bi = oi; }
        }
        if (lane == 0) {
          u64 tmp = selB[start + r];
          selB[start + r] = best;
          selB[start + bi] = tmp;
        }
      }
    } else if (n > 1) {
      u64 v = (lane < n) ? selB[start + lane] : 0ULL;    // real keys have MSB set -> pad sinks
#pragma unroll
      for (int k = 2; k <= 64; k <<= 1) {
#pragma unroll
        for (int j = k >> 1; j > 0; j >>= 1) {
          u64 o = __shfl_xor(v, j, 64);
          bool up = ((lane & k) == 0);                   // k=64 -> desc everywhere
          bool first = ((lane & j) == 0);
          u64 mx = v > o ? v : o, mn = v > o ? o : v;
          v = (first == up) ? mx : mn;
        }
      }
      if (lane < n) selB[start + lane] = v;
    }
  }
  __builtin_amdgcn_s_waitcnt(0);                         // selB writes visible to this wave
  // ---- fused gather for this wave's final segment [start, end) ----
  for (u32 pos = start + lane; pos < end; pos += 64) {
    u64 key = selB[pos];
    u32 n = ~(u32)key;
    size_t src = (size_t)b * NN + n;
    const float* bx = boxes + src * 7;
    float x = bx[0], y = bx[1], dx = bx[3], dy = bx[4];
    size_t gidx = ((size_t)b << 12) + pos;
    float* tb = topBox + gidx * 7;
#pragma unroll
    for (int c = 0; c < 7; ++c) tb[c] = bx[c];
    float4 p;
    p.x = x - 0.5f * dx; p.z = x + 0.5f * dx;   // 0.5*dx exact -> contraction-safe
    p.y = y - 0.5f * dy; p.w = y + 0.5f * dy;
    P[gidx] = p;
    AR[gidx] = dx * dy;
    topS[gidx] = unorderable((u32)(key >> 32));
    topL[gidx] = labels[src];
  }
}

// One 64x64 tile (rb, w) of the suppression mask. Lane = row; column boxes
// loaded from wave-uniform addresses (scalarizable). Fast path: inter > 0.7*denom
// with min-margin tracking; exact-IEEE-divide redo if any lane is in the band
// (rel 2e-5 >> max rounding skew ~4e-7) -> decisions bitwise == numpy.
// NEW: publishes rowAnyBm[b][rb] bit t = "row 64rb+t suppresses something in a
// FUTURE group (w > rb)" via one ballot + rare atomicOr -> the scan loads only
// rows that can actually change r (suppression is sparse: ~10/batch).
__device__ __forceinline__ void mask_tile(int b, int rb, int w, int lane,
                                          const float4* __restrict__ P,
                                          const float* __restrict__ AR,
                                          u64* __restrict__ maskT,
                                          u64* __restrict__ diag,
                                          u64* __restrict__ rowAnyBm) {
  int base = b << 12;
  int row = (rb << 6) + lane;
  float4 rp = P[base + row];
  float rar = AR[base + row];
  const float4* __restrict__ Pcol = P + base + (w << 6);   // wave-uniform base
  const float* __restrict__ ARcol = AR + base + (w << 6);
  u64 bits = 0;
  float margMin = 1.0f;
#pragma unroll 8
  for (int k = 0; k < 64; ++k) {
    float4 cb = Pcol[k];
    float ca = ARcol[k];
    float ix = fminf(rp.z, cb.z) - fmaxf(rp.x, cb.x); ix = fmaxf(0.0f, ix);
    float iy = fminf(rp.w, cb.w) - fmaxf(rp.y, cb.y); iy = fmaxf(0.0f, iy);
    float inter = ix * iy;
    float denom = ((rar + ca) - inter) + 1e-6f;      // same op order as reference
    float t = 0.7f * denom;                          // denom >= 1 here, t > 0
    bits |= ((u64)(inter > t ? 1u : 0u)) << k;
    margMin = fminf(margMin, fabsf(inter - t) - 2e-5f * t);
  }
  if (__any(margMin <= 0.0f)) {                      // rare: near-threshold lane
    bits = 0;
    for (int k = 0; k < 64; ++k) {
      float4 cb = Pcol[k];
      float ca = ARcol[k];
      float ix = fminf(rp.z, cb.z) - fmaxf(rp.x, cb.x); ix = fmaxf(0.0f, ix);
      float iy = fminf(rp.w, cb.w) - fmaxf(rp.y, cb.y); iy = fmaxf(0.0f, iy);
      float inter = ix * iy;
      float denom = ((rar + ca) - inter) + 1e-6f;
      bits |= ((u64)(((inter / denom) > NMS_TH) ? 1u : 0u)) << k;
    }
  }
  maskT[((size_t)(b * 64 + w)) * PRE + row] = bits;  // word-major: coalesced 512B
  if (w == rb) diag[base + row] = bits;
  else {
    u64 anyw = __ballot(bits != 0ULL);               // rows of this rb with future bits
    if (lane == 0 && anyw)
      atomicOr((unsigned long long*)&rowAnyBm[b * 64 + rb], anyw);
  }
}

// Phase 1: tiles with rb < P1G (rows 0..1023), w >= rb. 904 tiles/batch.
__global__ __launch_bounds__(256) void mask1_kernel(const float4* __restrict__ P,
                                                    const float* __restrict__ AR,
                                                    u64* __restrict__ maskT,
                                                    u64* __restrict__ diag,
                                                    u64* __restrict__ rowAnyBm) {
  int b = blockIdx.y;
  int ti = blockIdx.x * 4 + (threadIdx.x >> 6);       // [0, 904)
  int lane = threadIdx.x & 63;
  int rb = 0;                                         // row start(rb) = 64rb - rb(rb-1)/2
  while (rb < P1G - 1 && (64 * (rb + 1) - ((rb + 1) * rb) / 2) <= ti) ++rb;
  int w = rb + (ti - (64 * rb - (rb * (rb - 1)) / 2));
  mask_tile(b, rb, w, lane, P, AR, maskT, diag, rowAnyBm);
}

// Phase 2: tiles with rb >= P1G; no-op when scan phase 0 already found 512 keeps.
__global__ __launch_bounds__(256) void mask2_kernel(const float4* __restrict__ P,
                                                    const float* __restrict__ AR,
                                                    u64* __restrict__ maskT,
                                                    u64* __restrict__ diag,
                                                    u64* __restrict__ rowAnyBm,
                                                    const u32* __restrict__ doneFlag) {
  int b = blockIdx.y;
  if (doneFlag[b]) return;
  int ti = blockIdx.x * 4 + (threadIdx.x >> 6);       // [0, 1176)
  int lane = threadIdx.x & 63;
  int rr = 0;                                         // row start(rr) = 48rr - rr(rr-1)/2
  while (rr < 47 && (48 * (rr + 1) - ((rr + 1) * rr) / 2) <= ti) ++rr;
  int rb = rr + P1G;
  int w = rb + (ti - (48 * rr - (rr * (rr - 1)) / 2));
  mask_tile(b, rb, w, lane, P, AR, maskT, diag, rowAnyBm);
}

// Greedy scan, group-of-64, two-phase with state carry. One wave per batch.
// Per group: SALU decision recurrence (ballot fast-path when no diag bits);
// remv update loads ONLY rows flagged in rowAnyBm & keep (~10 rows/batch total,
// exact: unflagged rows have all-zero future words; the diagonal word only
// feeds r[g], which is read before group g's update and never again).
__global__ __launch_bounds__(64, 1) void scan_kernel(const u64* __restrict__ maskT,
                                                     const u64* __restrict__ diag,
                                                     const u64* __restrict__ rowAnyBm,
                                                     const float* __restrict__ topBox,
                                                     const float* __restrict__ topS,
                                                     const int* __restrict__ topL,
                                                     float* __restrict__ out,
                                                     u64* __restrict__ rState,
                                                     u64* __restrict__ kwState,
                                                     u32* __restrict__ nkState,
                                                     u32* __restrict__ doneFlag,
                                                     int phase) {
  __shared__ u64 kwLDS[64];
  int b = blockIdx.x;
  int lane = threadIdx.x;
  if (phase == 1 && doneFlag[b]) return;
  const u64* m = maskT + (size_t)b * 64 * PRE;
  const u64* dg = diag + (size_t)b * PRE;
  u64 rowAnyW = rowAnyBm[b * 64 + lane];             // lane g holds group g's word
  u64 r; int nk, gs, ge;
  if (phase == 0) {
    kwLDS[lane] = 0; r = 0; nk = 0; gs = 0; ge = P1G;
  } else {
    kwLDS[lane] = (lane < P1G) ? kwState[b * 64 + lane] : 0;
    r = rState[b * 64 + lane]; nk = nkState[b]; gs = P1G; ge = 64;
  }
  __syncthreads();
  bool done = false;
  u64 d_next = dg[(size_t)gs * 64 + lane];           // diag prefetch, 1 group ahead
  for (int g = gs; g < ge; ++g) {
    u64 d_cur = d_next;
    if (g + 1 < ge) d_next = dg[(size_t)(g + 1) * 64 + lane];
    // ---- decision: fast path (no intra-group suppression bits) or recurrence ----
    u64 sup = readlane64(r, g);
    u64 keep;
    u64 anyd = __ballot(d_cur != 0ULL);              // rows with any diag bits
    if (anyd == 0ULL) {
      keep = ~sup;                                   // no recurrence needed
    } else {
      keep = 0;
#pragma unroll
      for (int k = 0; k < 64; ++k) {
        u64 dk = readlane64(d_cur, k);               // compile-time lane index
        u64 bit = (sup >> k) & 1ULL;
        keep |= (bit ^ 1ULL) << k;
        sup |= (dk & ~((2ULL << k) - 1ULL)) & (bit - 1ULL);
      }
    }
    // ---- remv update: load only kept rows that can suppress future groups ----
    u64 need = keep & readlane64(rowAnyW, g);
    if (need) {
      u64 accr = 0;
      do {
        int t = __ffsll((long long)need) - 1;
        need &= need - 1;
        accr |= m[(size_t)lane * PRE + (size_t)(g << 6) + t];
      } while (need);
      r |= accr;
    }
    if (lane == 0) kwLDS[g] = keep;
    nk += (int)__popcll(keep);                       // uniform -> s_bcnt1
    if (nk >= POST) { done = true; break; }
  }
  __syncthreads();
  if (phase == 0 && !done) {                       // save state for phase 1
    rState[b * 64 + lane] = r;
    if (lane < P1G) kwState[b * 64 + lane] = kwLDS[lane];
    if (lane == 0) { nkState[b] = nk; doneFlag[b] = 0; }
    return;
  }
  if (phase == 0 && lane == 0) doneFlag[b] = 1;
  // ---- finalize: expand keep words, write output directly ----
  u64 kw = kwLDS[lane];
  int cnt = __popcll(kw);
  int pfx = cnt;
#pragma unroll
  for (int d = 1; d < 64; d <<= 1) {
    int up = __shfl_up(pfx, d, 64);
    if (lane >= d) pfx += up;
  }
  int total = __shfl(pfx, 63, 64);
  int pos = pfx - cnt;
  float* outR = out;
  float* outS = out + BB * POST * 7;
  float* outL = outS + BB * POST;
  while (kw) {
    int t = __ffsll((long long)kw) - 1;
    kw &= kw - 1;
    if (pos < POST) {
      int i = (lane << 6) + t;
      int g = (b << 9) + pos;
      const float* tb = topBox + ((size_t)(b << 12) + i) * 7;
#pragma unroll
      for (int c = 0; c < 7; ++c) outR[(size_t)g * 7 + c] = tb[c];
      outS[g] = topS[(b << 12) + i];
      outL[g] = (float)(topL[(b << 12) + i] + 1);
    }
    ++pos;
  }
  int fin = total < POST ? total : POST;
  for (int s = fin + lane; s < POST; s += 64) {     // empty slots: 0 / 0 / label 1
    int g = (b << 9) + s;
#pragma unroll
    for (int c = 0; c < 7; ++c) outR[(size_t)g * 7 + c] = 0.0f;
    outS[g] = 0.0f;
    outL[g] = 1.0f;
  }
}

extern "C" void kernel_launch(void* const* d_in, const int* in_sizes, int n_in,
                              void* d_out, int out_size, void* d_ws, size_t ws_size,
                              hipStream_t stream) {
  const float* boxes = (const float*)d_in[0];   // (4,32768,7)
  const float* cls   = (const float*)d_in[1];   // (4,32768,3)
  float* out = (float*)d_out;

  // ---- workspace carve-up (~11 MB) ----
  char* p = (char*)d_ws;
  auto take = [&](size_t bytes) { char* r = p; p += (bytes + 255) & ~(size_t)255; return (void*)r; };
  u64*   keys    = (u64*)  take((size_t)BB * NN * 8);
  int*   labels  = (int*)  take((size_t)BB * NN * 4);
  u32*   hist    = (u32*)  take((size_t)BB * 2048 * 4);
  u32*   selinfo = (u32*)  take((size_t)BB * 2 * 4);
  u32*   sfxBuf  = (u32*)  take((size_t)BB * 2048 * 4);
  u32*   cursor  = (u32*)  take((size_t)BB * 2048 * 4);
  u32*   cnt_mid = (u32*)  take((size_t)BB * 4);
  u64*   sel     = (u64*)  take((size_t)BB * PRE * 8);
  u64*   mid     = (u64*)  take((size_t)BB * MIDCAP * 8);
  float* topBox  = (float*)take((size_t)BB * PRE * 7 * 4);
  float4* Pb     = (float4*)take((size_t)BB * PRE * 16);
  float* AR      = (float*)take((size_t)BB * PRE * 4);
  float* topS    = (float*)take((size_t)BB * PRE * 4);
  int*   topL    = (int*)  take((size_t)BB * PRE * 4);
  u64*   maskT   = (u64*)  take((size_t)BB * 64 * PRE * 8);
  u64*   diagBuf = (u64*)  take((size_t)BB * PRE * 8);
  u64*   rowAny  = (u64*)  take((size_t)BB * 64 * 8);
  u64*   rState  = (u64*)  take((size_t)BB * 64 * 8);
  u64*   kwState = (u64*)  take((size_t)BB * 64 * 8);
  u32*   nkState = (u32*)  take((size_t)BB * 4);
  u32*   doneFlg = (u32*)  take((size_t)BB * 4);

  zero_kernel<<<32, 256, 0, stream>>>(hist, cnt_mid, rowAny);
  score_hist_kernel<<<BB * NN / 256, 256, 0, stream>>>(cls, labels, keys, hist);
  select_kernel<<<BB, 256, 0, stream>>>(hist, selinfo, sfxBuf, cursor);
  compact_kernel<<<BB * NN / 256, 256, 0, stream>>>(keys, selinfo, cursor, sel, mid, cnt_mid);
  bsort_kernel<<<BB * 2048, 64, 0, stream>>>(sel, mid, sfxBuf, selinfo, cnt_mid,
                                             boxes, labels, topBox, Pb, AR, topS, topL);
  mask1_kernel<<<dim3(226, BB), 256, 0, stream>>>(Pb, AR, maskT, diagBuf, rowAny);
  scan_kernel<<<BB, 64, 0, stream>>>(maskT, diagBuf, rowAny, topBox, topS, topL, out,
                                     rState, kwState, nkState, doneFlg, 0);
  mask2_kernel<<<dim3(294, BB), 256, 0, stream>>>(Pb, AR, maskT, diagBuf, rowAny, doneFlg);
  scan_kernel<<<BB, 64, 0, stream>>>(maskT, diagBuf, rowAny, topBox, topS, topL, out,
                                     rState, kwState, nkState, doneFlg, 1);
}

// Round 14
// 91.162 us; speedup vs baseline: 1.1676x; 1.1178x over previous
//
#include <hip/hip_runtime.h>
#include <stdint.h>

#define BB 4
#define NN 32768
#define PRE 4096
#define POST 512
#define NMS_TH 0.7f
#define MIDCAP 8192
#define P1G 16            // phase-1 groups (rows 0..1023)

typedef unsigned long long u64;
typedef unsigned int u32;

__device__ __forceinline__ u32 orderable(float f) {
  u32 u = __float_as_uint(f);
  return (u & 0x80000000u) ? ~u : (u | 0x80000000u);
}
__device__ __forceinline__ float unorderable(u32 o) {
  u32 u = (o & 0x80000000u) ? (o & 0x7fffffffu) : ~o;
  return __uint_as_float(u);
}
// Monotone fixed-point bucket: uniform in score space (scores in [0,1)).
__device__ __forceinline__ u32 bucket_of(float s) {
  u32 v = (u32)(s * 2147483648.0f);
  u32 bk = v >> 20;
  return bk > 2047u ? 2047u : bk;
}
// Wave-uniform 64-bit readlane (2x v_readlane -> SGPRs). Lane index may be a
// runtime uniform value.
__device__ __forceinline__ u64 readlane64(u64 v, int l) {
  u32 lo = (u32)__builtin_amdgcn_readlane((int)(u32)v, l);
  u32 hi = (u32)__builtin_amdgcn_readlane((int)(u32)(v >> 32), l);
  return ((u64)hi << 32) | lo;
}

// Zero histogram + mid counter + row-any bitmap (ws not re-poisoned between replays).
__global__ void zero_kernel(u32* __restrict__ hist, u32* __restrict__ cnt_mid,
                            u64* __restrict__ rowAnyBm) {
  int t = blockIdx.x * 256 + threadIdx.x;
  if (t < BB * 2048) hist[t] = 0;
  if (t < BB * 64) rowAnyBm[t] = 0;
  if (t < BB) cnt_mid[t] = 0;
}

// score = max over 3 classes, label = first argmax, key = orderable(score)||~idx.
// Histogram fixed-point bucket per batch.
__global__ __launch_bounds__(256) void score_hist_kernel(const float* __restrict__ cls,
                                                         int* __restrict__ labels,
                                                         u64* __restrict__ keys,
                                                         u32* __restrict__ hist) {
  __shared__ u32 lh[2048];
  for (int t = threadIdx.x; t < 2048; t += 256) lh[t] = 0;
  __syncthreads();
  int g = blockIdx.x * 256 + threadIdx.x;           // BB*NN is an exact multiple of 256
  const float* c = cls + (size_t)g * 3;
  float s = c[0]; int l = 0;
  float c1 = c[1], c2 = c[2];
  if (c1 > s) { s = c1; l = 1; }
  if (c2 > s) { s = c2; l = 2; }
  int n = g & (NN - 1);
  keys[g] = ((u64)orderable(s) << 32) | (u32)(~(u32)n);
  labels[g] = l;
  atomicAdd(&lh[bucket_of(s)], 1u);
  __syncthreads();
  int b = blockIdx.x >> 7;                           // 128 blocks per batch
  for (int t = threadIdx.x; t < 2048; t += 256) {
    u32 v = lh[t];
    if (v) atomicAdd(&hist[b * 2048 + t], v);
  }
}

// Per batch: suffix-scan the histogram; find threshold bucket T with
// count(>T) < PRE <= count(>=T); persist sfx and init per-bucket cursors
// (cursor[t] = start of bucket t's segment in the final descending order).
__global__ __launch_bounds__(256) void select_kernel(const u32* __restrict__ hist,
                                                     u32* __restrict__ selinfo,
                                                     u32* __restrict__ sfxBuf,
                                                     u32* __restrict__ cursor) {
  __shared__ u32 sfx[2048];
  int b = blockIdx.x;
  for (int t = threadIdx.x; t < 2048; t += 256) sfx[t] = hist[b * 2048 + t];
  __syncthreads();
  for (int d = 1; d < 2048; d <<= 1) {
    u32 v[8];
#pragma unroll
    for (int i = 0; i < 8; ++i) {
      int t = threadIdx.x + i * 256;
      v[i] = (t + d < 2048) ? sfx[t + d] : 0;
    }
    __syncthreads();
#pragma unroll
    for (int i = 0; i < 8; ++i) sfx[threadIdx.x + i * 256] += v[i];
    __syncthreads();
  }
  for (int t = threadIdx.x; t < 2048; t += 256) {
    u32 above = (t + 1 < 2048) ? sfx[t + 1] : 0;
    sfxBuf[b * 2048 + t] = sfx[t];
    cursor[b * 2048 + t] = above;                       // segment base
    if (above < PRE && sfx[t] >= PRE) { selinfo[b * 2] = (u32)t; selinfo[b * 2 + 1] = above; }
  }
}

// Compact: hi keys scatter directly into their bucket's segment of sel via
// per-bucket cursors (2048 addresses/batch -> low contention); mid keys go to
// the tie-break buffer. Within-segment order arbitrary; bsort fixes it.
__global__ __launch_bounds__(256) void compact_kernel(const u64* __restrict__ keys,
                                                      const u32* __restrict__ selinfo,
                                                      u32* __restrict__ cursor,
                                                      u64* __restrict__ sel, u64* __restrict__ mid,
                                                      u32* __restrict__ cnt_mid) {
  int g = blockIdx.x * 256 + threadIdx.x;
  int b = g >> 15;
  u64 key = keys[g];
  u32 bk = bucket_of(unorderable((u32)(key >> 32)));
  u32 T = selinfo[b * 2];
  if (bk > T) {
    u32 p = atomicAdd(&cursor[b * 2048 + bk], 1u);
    sel[((size_t)b << 12) + p] = key;
  } else if (bk == T) {
    u32 p = atomicAdd(&cnt_mid[b], 1u);
    if (p < MIDCAP) mid[(size_t)b * MIDCAP + p] = key;   // ~45 expected with this data
  }
}

// One wave per (batch, bucket). Buckets > T: in-register 64-lane bitonic sort
// of the segment. Bucket == T: top (PRE-C1) mid keys by wave argmax (fused
// midsel). Then: FUSED GATHER — each wave gathers box data for its final
// segment of sel.
__global__ __launch_bounds__(64) void bsort_kernel(u64* __restrict__ sel, u64* __restrict__ mid,
                                                   const u32* __restrict__ sfxBuf,
                                                   const u32* __restrict__ selinfo,
                                                   const u32* __restrict__ cnt_mid,
                                                   const float* __restrict__ boxes,
                                                   const int* __restrict__ labels,
                                                   float* __restrict__ topBox,
                                                   float4* __restrict__ P,
                                                   float* __restrict__ AR,
                                                   float* __restrict__ topS,
                                                   int* __restrict__ topL) {
  int t = blockIdx.x & 2047;
  int b = blockIdx.x >> 11;
  int lane = threadIdx.x;
  u32 T = selinfo[b * 2];
  if ((u32)t < T) return;
  u64* selB = sel + ((size_t)b << 12);
  u32 start, end;
  if ((u32)t == T) {
    u32 C1 = selinfo[b * 2 + 1];
    int need = PRE - (int)C1;
    int M = (int)cnt_mid[b]; if (M > MIDCAP) M = MIDCAP;
    u64* midB = mid + (size_t)b * MIDCAP;
    for (int r = 0; r < need; ++r) {
      u64 best = 0; int bi = -1;
      for (int q = lane; q < M; q += 64) {
        u64 v = midB[q];
        if (v > best) { best = v; bi = q; }
      }
#pragma unroll
      for (int d = 32; d > 0; d >>= 1) {
        u64 ob = __shfl_xor(best, d, 64);
        int oi = __shfl_xor(bi, d, 64);
        if (ob > best) { best = ob; bi = oi; }
      }
      if (lane == 0) selB[C1 + r] = best;
      if (bi >= 0 && lane == (bi & 63)) midB[bi] = 0;    // remove chosen
    }
    start = C1; end = PRE;
  } else {
    start = (t < 2047) ? sfxBuf[b * 2048 + t + 1] : 0u;
    end = sfxBuf[b * 2048 + t];
    int n = (int)(end - start);
    if (n > 64) {
      // robustness fallback (never hit on bench data): selection sort by wave argmax
      for (int r = 0; r < n - 1; ++r) {
        u64 best = 0; int bi = -1;
        for (int q = r + lane; q < n; q += 64) {
          u64 v = selB[start + q];
          if (v > best) { best = v; bi = q; }
        }
#pragma unroll
        for (int d = 32; d > 0; d >>= 1) {
          u64 ob = __shfl_xor(best, d, 64);
          int oi = __shfl_xor(bi, d, 64);
          if (ob > best) { best = ob; bi = oi; }
        }
        if (lane == 0) {
          u64 tmp = selB[start + r];
          selB[start + r] = best;
          selB[start + bi] = tmp;
        }
      }
    } else if (n > 1) {
      u64 v = (lane < n) ? selB[start + lane] : 0ULL;    // real keys have MSB set -> pad sinks
#pragma unroll
      for (int k = 2; k <= 64; k <<= 1) {
#pragma unroll
        for (int j = k >> 1; j > 0; j >>= 1) {
          u64 o = __shfl_xor(v, j, 64);
          bool up = ((lane & k) == 0);                   // k=64 -> desc everywhere
          bool first = ((lane & j) == 0);
          u64 mx = v > o ? v : o, mn = v > o ? o : v;
          v = (first == up) ? mx : mn;
        }
      }
      if (lane < n) selB[start + lane] = v;
    }
  }
  __builtin_amdgcn_s_waitcnt(0);                         // selB writes visible to this wave
  // ---- fused gather for this wave's final segment [start, end) ----
  for (u32 pos = start + lane; pos < end; pos += 64) {
    u64 key = selB[pos];
    u32 n = ~(u32)key;
    size_t src = (size_t)b * NN + n;
    const float* bx = boxes + src * 7;
    float x = bx[0], y = bx[1], dx = bx[3], dy = bx[4];
    size_t gidx = ((size_t)b << 12) + pos;
    float* tb = topBox + gidx * 7;
#pragma unroll
    for (int c = 0; c < 7; ++c) tb[c] = bx[c];
    float4 p;
    p.x = x - 0.5f * dx; p.z = x + 0.5f * dx;   // 0.5*dx exact -> contraction-safe
    p.y = y - 0.5f * dy; p.w = y + 0.5f * dy;
    P[gidx] = p;
    AR[gidx] = dx * dy;
    topS[gidx] = unorderable((u32)(key >> 32));
    topL[gidx] = labels[src];
  }
}

// One 64x64 tile (rb, w) of the suppression mask. Lane = row; column boxes
// loaded from wave-uniform addresses (scalarizable). Fast path: inter > 0.7*denom
// with min-margin tracking; exact-IEEE-divide redo if any lane is in the band
// (rel 2e-5 >> max rounding skew ~4e-7) -> decisions bitwise == numpy.
// Publishes rowAnyBm[b][rb] bit t = "row 64rb+t suppresses something in a
// FUTURE group (w > rb)" via one ballot + rare atomicOr.
__device__ __forceinline__ void mask_tile(int b, int rb, int w, int lane,
                                          const float4* __restrict__ P,
                                          const float* __restrict__ AR,
                                          u64* __restrict__ maskT,
                                          u64* __restrict__ diag,
                                          u64* __restrict__ rowAnyBm) {
  int base = b << 12;
  int row = (rb << 6) + lane;
  float4 rp = P[base + row];
  float rar = AR[base + row];
  const float4* __restrict__ Pcol = P + base + (w << 6);   // wave-uniform base
  const float* __restrict__ ARcol = AR + base + (w << 6);
  u64 bits = 0;
  float margMin = 1.0f;
#pragma unroll 8
  for (int k = 0; k < 64; ++k) {
    float4 cb = Pcol[k];
    float ca = ARcol[k];
    float ix = fminf(rp.z, cb.z) - fmaxf(rp.x, cb.x); ix = fmaxf(0.0f, ix);
    float iy = fminf(rp.w, cb.w) - fmaxf(rp.y, cb.y); iy = fmaxf(0.0f, iy);
    float inter = ix * iy;
    float denom = ((rar + ca) - inter) + 1e-6f;      // same op order as reference
    float t = 0.7f * denom;                          // denom >= 1 here, t > 0
    bits |= ((u64)(inter > t ? 1u : 0u)) << k;
    margMin = fminf(margMin, fabsf(inter - t) - 2e-5f * t);
  }
  if (__any(margMin <= 0.0f)) {                      // rare: near-threshold lane
    bits = 0;
    for (int k = 0; k < 64; ++k) {
      float4 cb = Pcol[k];
      float ca = ARcol[k];
      float ix = fminf(rp.z, cb.z) - fmaxf(rp.x, cb.x); ix = fmaxf(0.0f, ix);
      float iy = fminf(rp.w, cb.w) - fmaxf(rp.y, cb.y); iy = fmaxf(0.0f, iy);
      float inter = ix * iy;
      float denom = ((rar + ca) - inter) + 1e-6f;
      bits |= ((u64)(((inter / denom) > NMS_TH) ? 1u : 0u)) << k;
    }
  }
  maskT[((size_t)(b * 64 + w)) * PRE + row] = bits;  // word-major: coalesced 512B
  if (w == rb) diag[base + row] = bits;
  else {
    u64 anyw = __ballot(bits != 0ULL);               // rows of this rb with future bits
    if (lane == 0 && anyw)
      atomicOr((unsigned long long*)&rowAnyBm[b * 64 + rb], anyw);
  }
}

// Phase 1: tiles with rb < P1G (rows 0..1023), w >= rb. 904 tiles/batch.
__global__ __launch_bounds__(256) void mask1_kernel(const float4* __restrict__ P,
                                                    const float* __restrict__ AR,
                                                    u64* __restrict__ maskT,
                                                    u64* __restrict__ diag,
                                                    u64* __restrict__ rowAnyBm) {
  int b = blockIdx.y;
  int ti = blockIdx.x * 4 + (threadIdx.x >> 6);       // [0, 904)
  int lane = threadIdx.x & 63;
  int rb = 0;                                         // row start(rb) = 64rb - rb(rb-1)/2
  while (rb < P1G - 1 && (64 * (rb + 1) - ((rb + 1) * rb) / 2) <= ti) ++rb;
  int w = rb + (ti - (64 * rb - (rb * (rb - 1)) / 2));
  mask_tile(b, rb, w, lane, P, AR, maskT, diag, rowAnyBm);
}

// Phase 2: tiles with rb >= P1G; no-op when scan phase 0 already found 512 keeps.
__global__ __launch_bounds__(256) void mask2_kernel(const float4* __restrict__ P,
                                                    const float* __restrict__ AR,
                                                    u64* __restrict__ maskT,
                                                    u64* __restrict__ diag,
                                                    u64* __restrict__ rowAnyBm,
                                                    const u32* __restrict__ doneFlag) {
  int b = blockIdx.y;
  if (doneFlag[b]) return;
  int ti = blockIdx.x * 4 + (threadIdx.x >> 6);       // [0, 1176)
  int lane = threadIdx.x & 63;
  int rr = 0;                                         // row start(rr) = 48rr - rr(rr-1)/2
  while (rr < 47 && (48 * (rr + 1) - ((rr + 1) * rr) / 2) <= ti) ++rr;
  int rb = rr + P1G;
  int w = rb + (ti - (48 * rr - (rr * (rr - 1)) / 2));
  mask_tile(b, rb, w, lane, P, AR, maskT, diag, rowAnyBm);
}

// Greedy scan, group-of-64, two-phase with state carry. One wave per batch.
// R14 fixes (the 40us culprit was the recurrence running EVERY group — the old
// ballot test could never be 0 because diag words contain self-bits):
//  (a) sparsity test uses bits STRICTLY ABOVE the row (self/below-diag bits
//      can't suppress anyone later) -> fast path fires ~98% of groups;
//  (b) slow path iterates only over suppressor rows (runtime-lane readlane),
//      exact because row-k updates only set bits >k;
//  (c) diag words staged to LDS upfront (parallel coalesced loads) instead of
//      a serial 1-ahead HBM prefetch chain.
__global__ __launch_bounds__(64, 1) void scan_kernel(const u64* __restrict__ maskT,
                                                     const u64* __restrict__ diag,
                                                     const u64* __restrict__ rowAnyBm,
                                                     const float* __restrict__ topBox,
                                                     const float* __restrict__ topS,
                                                     const int* __restrict__ topL,
                                                     float* __restrict__ out,
                                                     u64* __restrict__ rState,
                                                     u64* __restrict__ kwState,
                                                     u32* __restrict__ nkState,
                                                     u32* __restrict__ doneFlag,
                                                     int phase) {
  __shared__ u64 kwLDS[64];
  __shared__ u64 dgLDS[3072];                        // max (64-P1G)*64
  int b = blockIdx.x;
  int lane = threadIdx.x;
  if (phase == 1 && doneFlag[b]) return;
  const u64* m = maskT + (size_t)b * 64 * PRE;
  const u64* dg = diag + (size_t)b * PRE;
  u64 rowAnyW = rowAnyBm[b * 64 + lane];             // lane g holds group g's word
  u64 r; int nk, gs, ge;
  if (phase == 0) {
    kwLDS[lane] = 0; r = 0; nk = 0; gs = 0; ge = P1G;
  } else {
    kwLDS[lane] = (lane < P1G) ? kwState[b * 64 + lane] : 0;
    r = rState[b * 64 + lane]; nk = nkState[b]; gs = P1G; ge = 64;
  }
  // stage this phase's diag words into LDS (parallel coalesced loads)
  for (int t = lane; t < (ge - gs) * 64; t += 64) dgLDS[t] = dg[(size_t)gs * 64 + t];
  __syncthreads();
  bool done = false;
  for (int g = gs; g < ge; ++g) {
    u64 d_cur = dgLDS[(g - gs) * 64 + lane];
    // rows with suppression bits STRICTLY ABOVE themselves (self/below can't matter)
    u64 aboveMask = ~((2ULL << lane) - 1ULL);        // lane=63 -> 0
    u64 rem = __ballot((d_cur & aboveMask) != 0ULL);
    u64 sup = readlane64(r, g);
    if (rem) {                                       // rare: real intra-group suppressors
      do {
        int k = __ffsll((long long)rem) - 1;
        rem &= rem - 1;
        if (!((sup >> k) & 1ULL))                    // row k kept -> apply its bits >k
          sup |= readlane64(d_cur, k) & ~((2ULL << k) - 1ULL);
      } while (rem);
    }
    u64 keep = ~sup;
    // ---- remv update: load only kept rows that can suppress future groups ----
    u64 need = keep & readlane64(rowAnyW, g);
    if (need) {
      u64 accr = 0;
      do {
        int t = __ffsll((long long)need) - 1;
        need &= need - 1;
        accr |= m[(size_t)lane * PRE + (size_t)(g << 6) + t];
      } while (need);
      r |= accr;
    }
    if (lane == 0) kwLDS[g] = keep;
    nk += (int)__popcll(keep);                       // uniform -> s_bcnt1
    if (nk >= POST) { done = true; break; }
  }
  __syncthreads();
  if (phase == 0 && !done) {                       // save state for phase 1
    rState[b * 64 + lane] = r;
    if (lane < P1G) kwState[b * 64 + lane] = kwLDS[lane];
    if (lane == 0) { nkState[b] = nk; doneFlag[b] = 0; }
    return;
  }
  if (phase == 0 && lane == 0) doneFlag[b] = 1;
  // ---- finalize: expand keep words, write output directly ----
  u64 kw = kwLDS[lane];
  int cnt = __popcll(kw);
  int pfx = cnt;
#pragma unroll
  for (int d = 1; d < 64; d <<= 1) {
    int up = __shfl_up(pfx, d, 64);
    if (lane >= d) pfx += up;
  }
  int total = __shfl(pfx, 63, 64);
  int pos = pfx - cnt;
  float* outR = out;
  float* outS = out + BB * POST * 7;
  float* outL = outS + BB * POST;
  while (kw) {
    int t = __ffsll((long long)kw) - 1;
    kw &= kw - 1;
    if (pos < POST) {
      int i = (lane << 6) + t;
      int g = (b << 9) + pos;
      const float* tb = topBox + ((size_t)(b << 12) + i) * 7;
#pragma unroll
      for (int c = 0; c < 7; ++c) outR[(size_t)g * 7 + c] = tb[c];
      outS[g] = topS[(b << 12) + i];
      outL[g] = (float)(topL[(b << 12) + i] + 1);
    }
    ++pos;
  }
  int fin = total < POST ? total : POST;
  for (int s = fin + lane; s < POST; s += 64) {     // empty slots: 0 / 0 / label 1
    int g = (b << 9) + s;
#pragma unroll
    for (int c = 0; c < 7; ++c) outR[(size_t)g * 7 + c] = 0.0f;
    outS[g] = 0.0f;
    outL[g] = 1.0f;
  }
}

extern "C" void kernel_launch(void* const* d_in, const int* in_sizes, int n_in,
                              void* d_out, int out_size, void* d_ws, size_t ws_size,
                              hipStream_t stream) {
  const float* boxes = (const float*)d_in[0];   // (4,32768,7)
  const float* cls   = (const float*)d_in[1];   // (4,32768,3)
  float* out = (float*)d_out;

  // ---- workspace carve-up (~11 MB) ----
  char* p = (char*)d_ws;
  auto take = [&](size_t bytes) { char* r = p; p += (bytes + 255) & ~(size_t)255; return (void*)r; };
  u64*   keys    = (u64*)  take((size_t)BB * NN * 8);
  int*   labels  = (int*)  take((size_t)BB * NN * 4);
  u32*   hist    = (u32*)  take((size_t)BB * 2048 * 4);
  u32*   selinfo = (u32*)  take((size_t)BB * 2 * 4);
  u32*   sfxBuf  = (u32*)  take((size_t)BB * 2048 * 4);
  u32*   cursor  = (u32*)  take((size_t)BB * 2048 * 4);
  u32*   cnt_mid = (u32*)  take((size_t)BB * 4);
  u64*   sel     = (u64*)  take((size_t)BB * PRE * 8);
  u64*   mid     = (u64*)  take((size_t)BB * MIDCAP * 8);
  float* topBox  = (float*)take((size_t)BB * PRE * 7 * 4);
  float4* Pb     = (float4*)take((size_t)BB * PRE * 16);
  float* AR      = (float*)take((size_t)BB * PRE * 4);
  float* topS    = (float*)take((size_t)BB * PRE * 4);
  int*   topL    = (int*)  take((size_t)BB * PRE * 4);
  u64*   maskT   = (u64*)  take((size_t)BB * 64 * PRE * 8);
  u64*   diagBuf = (u64*)  take((size_t)BB * PRE * 8);
  u64*   rowAny  = (u64*)  take((size_t)BB * 64 * 8);
  u64*   rState  = (u64*)  take((size_t)BB * 64 * 8);
  u64*   kwState = (u64*)  take((size_t)BB * 64 * 8);
  u32*   nkState = (u32*)  take((size_t)BB * 4);
  u32*   doneFlg = (u32*)  take((size_t)BB * 4);

  zero_kernel<<<32, 256, 0, stream>>>(hist, cnt_mid, rowAny);
  score_hist_kernel<<<BB * NN / 256, 256, 0, stream>>>(cls, labels, keys, hist);
  select_kernel<<<BB, 256, 0, stream>>>(hist, selinfo, sfxBuf, cursor);
  compact_kernel<<<BB * NN / 256, 256, 0, stream>>>(keys, selinfo, cursor, sel, mid, cnt_mid);
  bsort_kernel<<<BB * 2048, 64, 0, stream>>>(sel, mid, sfxBuf, selinfo, cnt_mid,
                                             boxes, labels, topBox, Pb, AR, topS, topL);
  mask1_kernel<<<dim3(226, BB), 256, 0, stream>>>(Pb, AR, maskT, diagBuf, rowAny);
  scan_kernel<<<BB, 64, 0, stream>>>(maskT, diagBuf, rowAny, topBox, topS, topL, out,
                                     rState, kwState, nkState, doneFlg, 0);
  mask2_kernel<<<dim3(294, BB), 256, 0, stream>>>(Pb, AR, maskT, diagBuf, rowAny, doneFlg);
  scan_kernel<<<BB, 64, 0, stream>>>(maskT, diagBuf, rowAny, topBox, topS, topL, out,
                                     rState, kwState, nkState, doneFlg, 1);
}

// Round 15
// 85.903 us; speedup vs baseline: 1.2391x; 1.0612x over previous
//
#include <hip/hip_runtime.h>
#include <stdint.h>

#define BB 4
#define NN 32768
#define PRE 4096
#define POST 512
#define NMS_TH 0.7f
#define MIDCAP 8192
#define P1G 10            // phase-1 groups (rows 0..639); 512th keep lands ~i=525
#define T1 595            // phase-1 tiles/batch = sum_{rb=0..P1G-1}(64-rb)
#define T2 1485           // phase-2 tiles/batch = 2080 - T1

typedef unsigned long long u64;
typedef unsigned int u32;

__device__ __forceinline__ u32 orderable(float f) {
  u32 u = __float_as_uint(f);
  return (u & 0x80000000u) ? ~u : (u | 0x80000000u);
}
__device__ __forceinline__ float unorderable(u32 o) {
  u32 u = (o & 0x80000000u) ? (o & 0x7fffffffu) : ~o;
  return __uint_as_float(u);
}
// Monotone fixed-point bucket: uniform in score space (scores in [0,1)).
__device__ __forceinline__ u32 bucket_of(float s) {
  u32 v = (u32)(s * 2147483648.0f);
  u32 bk = v >> 20;
  return bk > 2047u ? 2047u : bk;
}
// Wave-uniform 64-bit readlane (2x v_readlane -> SGPRs). Lane index may be a
// runtime uniform value.
__device__ __forceinline__ u64 readlane64(u64 v, int l) {
  u32 lo = (u32)__builtin_amdgcn_readlane((int)(u32)v, l);
  u32 hi = (u32)__builtin_amdgcn_readlane((int)(u32)(v >> 32), l);
  return ((u64)hi << 32) | lo;
}

// Zero histogram + mid counter + row-any bitmap (ws not re-poisoned between replays).
__global__ void zero_kernel(u32* __restrict__ hist, u32* __restrict__ cnt_mid,
                            u64* __restrict__ rowAnyBm) {
  int t = blockIdx.x * 256 + threadIdx.x;
  if (t < BB * 2048) hist[t] = 0;
  if (t < BB * 64) rowAnyBm[t] = 0;
  if (t < BB) cnt_mid[t] = 0;
}

// score/label/key for 4 points per thread (vectorized: 3x float4 in,
// 2x ulonglong2 + int4 out — hipcc won't auto-vectorize the scalar form).
// Histogram fixed-point bucket per batch. Grid: BB*NN/1024 = 128 blocks.
__global__ __launch_bounds__(256) void score_hist_kernel(const float* __restrict__ cls,
                                                         int* __restrict__ labels,
                                                         u64* __restrict__ keys,
                                                         u32* __restrict__ hist) {
  __shared__ u32 lh[2048];
  for (int t = threadIdx.x; t < 2048; t += 256) lh[t] = 0;
  __syncthreads();
  int t4 = blockIdx.x * 256 + threadIdx.x;
  int base4 = t4 * 4;                               // first point id (batches 4-aligned)
  const float4* c4 = (const float4*)(cls + (size_t)t4 * 12);
  float4 va = c4[0], vb = c4[1], vc = c4[2];
  float v[12] = {va.x, va.y, va.z, va.w, vb.x, vb.y, vb.z, vb.w, vc.x, vc.y, vc.z, vc.w};
  u64 ks[4]; int ls[4];
#pragma unroll
  for (int p = 0; p < 4; ++p) {
    float s = v[3 * p]; int l = 0;
    if (v[3 * p + 1] > s) { s = v[3 * p + 1]; l = 1; }
    if (v[3 * p + 2] > s) { s = v[3 * p + 2]; l = 2; }
    int n = (base4 + p) & (NN - 1);
    ks[p] = ((u64)orderable(s) << 32) | (u32)(~(u32)n);
    ls[p] = l;
    atomicAdd(&lh[bucket_of(s)], 1u);
  }
  *(ulonglong2*)(keys + base4) = make_ulonglong2(ks[0], ks[1]);
  *(ulonglong2*)(keys + base4 + 2) = make_ulonglong2(ks[2], ks[3]);
  *(int4*)(labels + base4) = make_int4(ls[0], ls[1], ls[2], ls[3]);
  __syncthreads();
  int b = blockIdx.x >> 5;                           // 32 blocks per batch
  for (int t = threadIdx.x; t < 2048; t += 256) {
    u32 vv = lh[t];
    if (vv) atomicAdd(&hist[b * 2048 + t], vv);
  }
}

// Per batch: suffix-scan the histogram; find threshold bucket T with
// count(>T) < PRE <= count(>=T); persist sfx and init per-bucket cursors
// (cursor[t] = start of bucket t's segment in the final descending order).
__global__ __launch_bounds__(256) void select_kernel(const u32* __restrict__ hist,
                                                     u32* __restrict__ selinfo,
                                                     u32* __restrict__ sfxBuf,
                                                     u32* __restrict__ cursor) {
  __shared__ u32 sfx[2048];
  int b = blockIdx.x;
  for (int t = threadIdx.x; t < 2048; t += 256) sfx[t] = hist[b * 2048 + t];
  __syncthreads();
  for (int d = 1; d < 2048; d <<= 1) {
    u32 v[8];
#pragma unroll
    for (int i = 0; i < 8; ++i) {
      int t = threadIdx.x + i * 256;
      v[i] = (t + d < 2048) ? sfx[t + d] : 0;
    }
    __syncthreads();
#pragma unroll
    for (int i = 0; i < 8; ++i) sfx[threadIdx.x + i * 256] += v[i];
    __syncthreads();
  }
  for (int t = threadIdx.x; t < 2048; t += 256) {
    u32 above = (t + 1 < 2048) ? sfx[t + 1] : 0;
    sfxBuf[b * 2048 + t] = sfx[t];
    cursor[b * 2048 + t] = above;                       // segment base
    if (above < PRE && sfx[t] >= PRE) { selinfo[b * 2] = (u32)t; selinfo[b * 2 + 1] = above; }
  }
}

// Compact, 4 keys/thread (2x ulonglong2 loads): hi keys scatter into their
// bucket's segment via per-bucket cursors; mid keys to the tie-break buffer.
// Grid: BB*NN/1024 = 128 blocks.
__global__ __launch_bounds__(256) void compact_kernel(const u64* __restrict__ keys,
                                                      const u32* __restrict__ selinfo,
                                                      u32* __restrict__ cursor,
                                                      u64* __restrict__ sel, u64* __restrict__ mid,
                                                      u32* __restrict__ cnt_mid) {
  int t4 = blockIdx.x * 256 + threadIdx.x;
  int base4 = t4 * 4;
  int b = base4 >> 15;
  u32 T = selinfo[b * 2];
  ulonglong2 k01 = *(const ulonglong2*)(keys + base4);
  ulonglong2 k23 = *(const ulonglong2*)(keys + base4 + 2);
  u64 kk[4] = {k01.x, k01.y, k23.x, k23.y};
#pragma unroll
  for (int p = 0; p < 4; ++p) {
    u64 key = kk[p];
    u32 bk = bucket_of(unorderable((u32)(key >> 32)));
    if (bk > T) {
      u32 q = atomicAdd(&cursor[b * 2048 + bk], 1u);
      sel[((size_t)b << 12) + q] = key;
    } else if (bk == T) {
      u32 q = atomicAdd(&cnt_mid[b], 1u);
      if (q < MIDCAP) mid[(size_t)b * MIDCAP + q] = key;   // ~45 expected with this data
    }
  }
}

// One wave per (batch, bucket). Buckets > T: in-register 64-lane bitonic sort
// of the segment. Bucket == T: top (PRE-C1) mid keys by wave argmax (fused
// midsel). Then: FUSED GATHER — each wave gathers box data for its final
// segment of sel.
__global__ __launch_bounds__(64) void bsort_kernel(u64* __restrict__ sel, u64* __restrict__ mid,
                                                   const u32* __restrict__ sfxBuf,
                                                   const u32* __restrict__ selinfo,
                                                   const u32* __restrict__ cnt_mid,
                                                   const float* __restrict__ boxes,
                                                   const int* __restrict__ labels,
                                                   float* __restrict__ topBox,
                                                   float4* __restrict__ P,
                                                   float* __restrict__ AR,
                                                   float* __restrict__ topS,
                                                   int* __restrict__ topL) {
  int t = blockIdx.x & 2047;
  int b = blockIdx.x >> 11;
  int lane = threadIdx.x;
  u32 T = selinfo[b * 2];
  if ((u32)t < T) return;
  u64* selB = sel + ((size_t)b << 12);
  u32 start, end;
  if ((u32)t == T) {
    u32 C1 = selinfo[b * 2 + 1];
    int need = PRE - (int)C1;
    int M = (int)cnt_mid[b]; if (M > MIDCAP) M = MIDCAP;
    u64* midB = mid + (size_t)b * MIDCAP;
    for (int r = 0; r < need; ++r) {
      u64 best = 0; int bi = -1;
      for (int q = lane; q < M; q += 64) {
        u64 v = midB[q];
        if (v > best) { best = v; bi = q; }
      }
#pragma unroll
      for (int d = 32; d > 0; d >>= 1) {
        u64 ob = __shfl_xor(best, d, 64);
        int oi = __shfl_xor(bi, d, 64);
        if (ob > best) { best = ob; bi = oi; }
      }
      if (lane == 0) selB[C1 + r] = best;
      if (bi >= 0 && lane == (bi & 63)) midB[bi] = 0;    // remove chosen
    }
    start = C1; end = PRE;
  } else {
    start = (t < 2047) ? sfxBuf[b * 2048 + t + 1] : 0u;
    end = sfxBuf[b * 2048 + t];
    int n = (int)(end - start);
    if (n > 64) {
      // robustness fallback (never hit on bench data): selection sort by wave argmax
      for (int r = 0; r < n - 1; ++r) {
        u64 best = 0; int bi = -1;
        for (int q = r + lane; q < n; q += 64) {
          u64 v = selB[start + q];
          if (v > best) { best = v; bi = q; }
        }
#pragma unroll
        for (int d = 32; d > 0; d >>= 1) {
          u64 ob = __shfl_xor(best, d, 64);
          int oi = __shfl_xor(bi, d, 64);
          if (ob > best) { best = ob; bi = oi; }
        }
        if (lane == 0) {
          u64 tmp = selB[start + r];
          selB[start + r] = best;
          selB[start + bi] = tmp;
        }
      }
    } else if (n > 1) {
      u64 v = (lane < n) ? selB[start + lane] : 0ULL;    // real keys have MSB set -> pad sinks
#pragma unroll
      for (int k = 2; k <= 64; k <<= 1) {
#pragma unroll
        for (int j = k >> 1; j > 0; j >>= 1) {
          u64 o = __shfl_xor(v, j, 64);
          bool up = ((lane & k) == 0);                   // k=64 -> desc everywhere
          bool first = ((lane & j) == 0);
          u64 mx = v > o ? v : o, mn = v > o ? o : v;
          v = (first == up) ? mx : mn;
        }
      }
      if (lane < n) selB[start + lane] = v;
    }
  }
  __builtin_amdgcn_s_waitcnt(0);                         // selB writes visible to this wave
  // ---- fused gather for this wave's final segment [start, end) ----
  for (u32 pos = start + lane; pos < end; pos += 64) {
    u64 key = selB[pos];
    u32 n = ~(u32)key;
    size_t src = (size_t)b * NN + n;
    const float* bx = boxes + src * 7;
    float x = bx[0], y = bx[1], dx = bx[3], dy = bx[4];
    size_t gidx = ((size_t)b << 12) + pos;
    float* tb = topBox + gidx * 7;
#pragma unroll
    for (int c = 0; c < 7; ++c) tb[c] = bx[c];
    float4 p;
    p.x = x - 0.5f * dx; p.z = x + 0.5f * dx;   // 0.5*dx exact -> contraction-safe
    p.y = y - 0.5f * dy; p.w = y + 0.5f * dy;
    P[gidx] = p;
    AR[gidx] = dx * dy;
    topS[gidx] = unorderable((u32)(key >> 32));
    topL[gidx] = labels[src];
  }
}

// One 64x64 tile (rb, w) of the suppression mask. Lane = row; column boxes
// loaded from wave-uniform addresses (scalarizable). Fast path: inter > 0.7*denom
// with min-margin tracking; exact-IEEE-divide redo if any lane is in the band
// (rel 2e-5 >> max rounding skew ~4e-7) -> decisions bitwise == numpy.
// Publishes rowAnyBm[b][rb] bit t = "row 64rb+t suppresses something in a
// FUTURE group (w > rb)" via one ballot + rare atomicOr.
__device__ __forceinline__ void mask_tile(int b, int rb, int w, int lane,
                                          const float4* __restrict__ P,
                                          const float* __restrict__ AR,
                                          u64* __restrict__ maskT,
                                          u64* __restrict__ diag,
                                          u64* __restrict__ rowAnyBm) {
  int base = b << 12;
  int row = (rb << 6) + lane;
  float4 rp = P[base + row];
  float rar = AR[base + row];
  const float4* __restrict__ Pcol = P + base + (w << 6);   // wave-uniform base
  const float* __restrict__ ARcol = AR + base + (w << 6);
  u64 bits = 0;
  float margMin = 1.0f;
#pragma unroll 8
  for (int k = 0; k < 64; ++k) {
    float4 cb = Pcol[k];
    float ca = ARcol[k];
    float ix = fminf(rp.z, cb.z) - fmaxf(rp.x, cb.x); ix = fmaxf(0.0f, ix);
    float iy = fminf(rp.w, cb.w) - fmaxf(rp.y, cb.y); iy = fmaxf(0.0f, iy);
    float inter = ix * iy;
    float denom = ((rar + ca) - inter) + 1e-6f;      // same op order as reference
    float t = 0.7f * denom;                          // denom >= 1 here, t > 0
    bits |= ((u64)(inter > t ? 1u : 0u)) << k;
    margMin = fminf(margMin, fabsf(inter - t) - 2e-5f * t);
  }
  if (__any(margMin <= 0.0f)) {                      // rare: near-threshold lane
    bits = 0;
    for (int k = 0; k < 64; ++k) {
      float4 cb = Pcol[k];
      float ca = ARcol[k];
      float ix = fminf(rp.z, cb.z) - fmaxf(rp.x, cb.x); ix = fmaxf(0.0f, ix);
      float iy = fminf(rp.w, cb.w) - fmaxf(rp.y, cb.y); iy = fmaxf(0.0f, iy);
      float inter = ix * iy;
      float denom = ((rar + ca) - inter) + 1e-6f;
      bits |= ((u64)(((inter / denom) > NMS_TH) ? 1u : 0u)) << k;
    }
  }
  maskT[((size_t)(b * 64 + w)) * PRE + row] = bits;  // word-major: coalesced 512B
  if (w == rb) diag[base + row] = bits;
  else {
    u64 anyw = __ballot(bits != 0ULL);               // rows of this rb with future bits
    if (lane == 0 && anyw)
      atomicOr((unsigned long long*)&rowAnyBm[b * 64 + rb], anyw);
  }
}

// Phase 1: tiles with rb < P1G (rows 0..64*P1G-1), w >= rb. T1 tiles/batch.
__global__ __launch_bounds__(256) void mask1_kernel(const float4* __restrict__ P,
                                                    const float* __restrict__ AR,
                                                    u64* __restrict__ maskT,
                                                    u64* __restrict__ diag,
                                                    u64* __restrict__ rowAnyBm) {
  int b = blockIdx.y;
  int ti = blockIdx.x * 4 + (threadIdx.x >> 6);       // [0, T1)
  if (ti >= T1) return;
  int lane = threadIdx.x & 63;
  int rb = 0;                                         // row start(rb) = 64rb - rb(rb-1)/2
  while (rb < P1G - 1 && (64 * (rb + 1) - ((rb + 1) * rb) / 2) <= ti) ++rb;
  int w = rb + (ti - (64 * rb - (rb * (rb - 1)) / 2));
  mask_tile(b, rb, w, lane, P, AR, maskT, diag, rowAnyBm);
}

// Phase 2: tiles with rb >= P1G; no-op when scan phase 0 already found 512 keeps.
__global__ __launch_bounds__(256) void mask2_kernel(const float4* __restrict__ P,
                                                    const float* __restrict__ AR,
                                                    u64* __restrict__ maskT,
                                                    u64* __restrict__ diag,
                                                    u64* __restrict__ rowAnyBm,
                                                    const u32* __restrict__ doneFlag) {
  int b = blockIdx.y;
  if (doneFlag[b]) return;
  int ti = blockIdx.x * 4 + (threadIdx.x >> 6);       // [0, T2)
  if (ti >= T2) return;
  int lane = threadIdx.x & 63;
  // rows per rr: (64-P1G)-rr ; row start(rr) = (64-P1G)*rr - rr(rr-1)/2
  int R = 64 - P1G;
  int rr = 0;
  while (rr < R - 1 && (R * (rr + 1) - ((rr + 1) * rr) / 2) <= ti) ++rr;
  int rb = rr + P1G;
  int w = rb + (ti - (R * rr - (rr * (rr - 1)) / 2));
  mask_tile(b, rb, w, lane, P, AR, maskT, diag, rowAnyBm);
}

// Greedy scan, group-of-64, two-phase with state carry. One wave per batch.
// Sparsity-aware: fast path (strictly-above-diagonal ballot) fires ~98% of
// groups; sparse readlane recurrence otherwise; remv loads only flagged rows.
__global__ __launch_bounds__(64, 1) void scan_kernel(const u64* __restrict__ maskT,
                                                     const u64* __restrict__ diag,
                                                     const u64* __restrict__ rowAnyBm,
                                                     const float* __restrict__ topBox,
                                                     const float* __restrict__ topS,
                                                     const int* __restrict__ topL,
                                                     float* __restrict__ out,
                                                     u64* __restrict__ rState,
                                                     u64* __restrict__ kwState,
                                                     u32* __restrict__ nkState,
                                                     u32* __restrict__ doneFlag,
                                                     int phase) {
  __shared__ u64 kwLDS[64];
  __shared__ u64 dgLDS[(64 - P1G) * 64];             // phase-1 staging is the max
  int b = blockIdx.x;
  int lane = threadIdx.x;
  if (phase == 1 && doneFlag[b]) return;
  const u64* m = maskT + (size_t)b * 64 * PRE;
  const u64* dg = diag + (size_t)b * PRE;
  u64 rowAnyW = rowAnyBm[b * 64 + lane];             // lane g holds group g's word
  u64 r; int nk, gs, ge;
  if (phase == 0) {
    kwLDS[lane] = 0; r = 0; nk = 0; gs = 0; ge = P1G;
  } else {
    kwLDS[lane] = (lane < P1G) ? kwState[b * 64 + lane] : 0;
    r = rState[b * 64 + lane]; nk = nkState[b]; gs = P1G; ge = 64;
  }
  // stage this phase's diag words into LDS (parallel coalesced loads)
  for (int t = lane; t < (ge - gs) * 64; t += 64) dgLDS[t] = dg[(size_t)gs * 64 + t];
  __syncthreads();
  bool done = false;
  for (int g = gs; g < ge; ++g) {
    u64 d_cur = dgLDS[(g - gs) * 64 + lane];
    // rows with suppression bits STRICTLY ABOVE themselves (self/below can't matter)
    u64 aboveMask = ~((2ULL << lane) - 1ULL);        // lane=63 -> 0
    u64 rem = __ballot((d_cur & aboveMask) != 0ULL);
    u64 sup = readlane64(r, g);
    if (rem) {                                       // rare: real intra-group suppressors
      do {
        int k = __ffsll((long long)rem) - 1;
        rem &= rem - 1;
        if (!((sup >> k) & 1ULL))                    // row k kept -> apply its bits >k
          sup |= readlane64(d_cur, k) & ~((2ULL << k) - 1ULL);
      } while (rem);
    }
    u64 keep = ~sup;
    // ---- remv update: load only kept rows that can suppress future groups ----
    u64 need = keep & readlane64(rowAnyW, g);
    if (need) {
      u64 accr = 0;
      do {
        int t = __ffsll((long long)need) - 1;
        need &= need - 1;
        accr |= m[(size_t)lane * PRE + (size_t)(g << 6) + t];
      } while (need);
      r |= accr;
    }
    if (lane == 0) kwLDS[g] = keep;
    nk += (int)__popcll(keep);                       // uniform -> s_bcnt1
    if (nk >= POST) { done = true; break; }
  }
  __syncthreads();
  if (phase == 0 && !done) {                       // save state for phase 1
    rState[b * 64 + lane] = r;
    if (lane < P1G) kwState[b * 64 + lane] = kwLDS[lane];
    if (lane == 0) { nkState[b] = nk; doneFlag[b] = 0; }
    return;
  }
  if (phase == 0 && lane == 0) doneFlag[b] = 1;
  // ---- finalize: expand keep words, write output directly ----
  u64 kw = kwLDS[lane];
  int cnt = __popcll(kw);
  int pfx = cnt;
#pragma unroll
  for (int d = 1; d < 64; d <<= 1) {
    int up = __shfl_up(pfx, d, 64);
    if (lane >= d) pfx += up;
  }
  int total = __shfl(pfx, 63, 64);
  int pos = pfx - cnt;
  float* outR = out;
  float* outS = out + BB * POST * 7;
  float* outL = outS + BB * POST;
  while (kw) {
    int t = __ffsll((long long)kw) - 1;
    kw &= kw - 1;
    if (pos < POST) {
      int i = (lane << 6) + t;
      int g = (b << 9) + pos;
      const float* tb = topBox + ((size_t)(b << 12) + i) * 7;
#pragma unroll
      for (int c = 0; c < 7; ++c) outR[(size_t)g * 7 + c] = tb[c];
      outS[g] = topS[(b << 12) + i];
      outL[g] = (float)(topL[(b << 12) + i] + 1);
    }
    ++pos;
  }
  int fin = total < POST ? total : POST;
  for (int s = fin + lane; s < POST; s += 64) {     // empty slots: 0 / 0 / label 1
    int g = (b << 9) + s;
#pragma unroll
    for (int c = 0; c < 7; ++c) outR[(size_t)g * 7 + c] = 0.0f;
    outS[g] = 0.0f;
    outL[g] = 1.0f;
  }
}

extern "C" void kernel_launch(void* const* d_in, const int* in_sizes, int n_in,
                              void* d_out, int out_size, void* d_ws, size_t ws_size,
                              hipStream_t stream) {
  const float* boxes = (const float*)d_in[0];   // (4,32768,7)
  const float* cls   = (const float*)d_in[1];   // (4,32768,3)
  float* out = (float*)d_out;

  // ---- workspace carve-up (~11 MB) ----
  char* p = (char*)d_ws;
  auto take = [&](size_t bytes) { char* r = p; p += (bytes + 255) & ~(size_t)255; return (void*)r; };
  u64*   keys    = (u64*)  take((size_t)BB * NN * 8);
  int*   labels  = (int*)  take((size_t)BB * NN * 4);
  u32*   hist    = (u32*)  take((size_t)BB * 2048 * 4);
  u32*   selinfo = (u32*)  take((size_t)BB * 2 * 4);
  u32*   sfxBuf  = (u32*)  take((size_t)BB * 2048 * 4);
  u32*   cursor  = (u32*)  take((size_t)BB * 2048 * 4);
  u32*   cnt_mid = (u32*)  take((size_t)BB * 4);
  u64*   sel     = (u64*)  take((size_t)BB * PRE * 8);
  u64*   mid     = (u64*)  take((size_t)BB * MIDCAP * 8);
  float* topBox  = (float*)take((size_t)BB * PRE * 7 * 4);
  float4* Pb     = (float4*)take((size_t)BB * PRE * 16);
  float* AR      = (float*)take((size_t)BB * PRE * 4);
  float* topS    = (float*)take((size_t)BB * PRE * 4);
  int*   topL    = (int*)  take((size_t)BB * PRE * 4);
  u64*   maskT   = (u64*)  take((size_t)BB * 64 * PRE * 8);
  u64*   diagBuf = (u64*)  take((size_t)BB * PRE * 8);
  u64*   rowAny  = (u64*)  take((size_t)BB * 64 * 8);
  u64*   rState  = (u64*)  take((size_t)BB * 64 * 8);
  u64*   kwState = (u64*)  take((size_t)BB * 64 * 8);
  u32*   nkState = (u32*)  take((size_t)BB * 4);
  u32*   doneFlg = (u32*)  take((size_t)BB * 4);

  zero_kernel<<<32, 256, 0, stream>>>(hist, cnt_mid, rowAny);
  score_hist_kernel<<<BB * NN / 1024, 256, 0, stream>>>(cls, labels, keys, hist);
  select_kernel<<<BB, 256, 0, stream>>>(hist, selinfo, sfxBuf, cursor);
  compact_kernel<<<BB * NN / 1024, 256, 0, stream>>>(keys, selinfo, cursor, sel, mid, cnt_mid);
  bsort_kernel<<<BB * 2048, 64, 0, stream>>>(sel, mid, sfxBuf, selinfo, cnt_mid,
                                             boxes, labels, topBox, Pb, AR, topS, topL);
  mask1_kernel<<<dim3((T1 + 3) / 4, BB), 256, 0, stream>>>(Pb, AR, maskT, diagBuf, rowAny);
  scan_kernel<<<BB, 64, 0, stream>>>(maskT, diagBuf, rowAny, topBox, topS, topL, out,
                                     rState, kwState, nkState, doneFlg, 0);
  mask2_kernel<<<dim3((T2 + 3) / 4, BB), 256, 0, stream>>>(Pb, AR, maskT, diagBuf, rowAny, doneFlg);
  scan_kernel<<<BB, 64, 0, stream>>>(maskT, diagBuf, rowAny, topBox, topS, topL, out,
                                     rState, kwState, nkState, doneFlg, 1);
}